// Round 10
// baseline (44.395 us; speedup 1.0000x reference)
//
#include <hip/hip_runtime.h>

// Chamfer (bidirectional 1-NN mean of squared distances), two [16384,3] fp32 clouds.
// Round-10: same verified split-fp16 MFMA numerics (absmax 0.0 since R7).
// R8/R9 post-mortem: kernel stuck at ~30us vs ~10us overlapped floor -> latency-
// bound. R9 had only 2 blocks/CU and 2 waves/SIMD (VGPR cap 256). This round:
//  - keep 2 A-frags/wave (halved LDS traffic vs R8),
//  - NBSPLIT 4->8: 1024 blocks = 4 blocks/CU,
//  - __launch_bounds__(256,4): VGPR<=128 -> 4 waves/SIMD (2x latency hiding),
//  - inner loop sequenced so one d-tuple pair is live at a time (~116 live VGPR).
//
// MFMA formulation (one v_mfma_f32_32x32x16_f16 per 32x32 distance tile):
//   x = xh + xl (split fp16). K slots:
//     0..2 A=-2a_hi B=b_hi | 3..5 A=-2a_hi B=b_lo | 6..8 A=-2a_lo B=b_hi
//     9,10 A={a2_hi,a2_lo} B={1,1} | 11,12 A={1,1} B={b2_hi,b2_lo} | 13..15 zero
//   => D[i][j] = a2 + b2 - 2 a.b + O(3e-3), fp32 accumulators.

typedef _Float16 half8 __attribute__((ext_vector_type(8)));
typedef float floatx16 __attribute__((ext_vector_type(16)));

#define NPTS 16384
#define BLOCK 256
#define WAVES 4
#define TILE 32
#define ROWSW (2 * TILE)              // 64 A-rows per wave (2 fragments)
#define APB (WAVES * ROWSW)           // 256 A-points per block
#define NBSPLIT 8
#define BSWEEP (NPTS / NBSPLIT)       // 2048 B-points per block
#define CHUNKB 512                    // B-points staged in LDS at a time
#define NSTAGE (BSWEEP / CHUNKB)      // 4
#define TPS (CHUNKB / TILE)           // 16 tiles per stage

union H8 { _Float16 h[8]; uint4 u; };

// Pack both clouds into A-format and B-format fragments (32 B/point each),
// and initialize the partial-min array.
__global__ __launch_bounds__(256) void prep_kernel(
    const float* __restrict__ P0, const float* __restrict__ P1,
    uint4* __restrict__ Ap, uint4* __restrict__ Bp,
    unsigned* __restrict__ dmin_all)
{
    const int i = blockIdx.x * 256 + threadIdx.x;      // 0..2*NPTS-1
    dmin_all[i] = 0x7F7F7F7Fu;                         // 3.39e38 > any real distance

    const float* P = (i < NPTS) ? P0 : P1;
    const int k = (i < NPTS) ? i : i - NPTS;
    const float x = P[k * 3 + 0], y = P[k * 3 + 1], z = P[k * 3 + 2];
    const float q2 = x * x + y * y + z * z;

    const _Float16 xh = (_Float16)x; const float xl = x - (float)xh;
    const _Float16 yh = (_Float16)y; const float yl = y - (float)yh;
    const _Float16 zh = (_Float16)z; const float zl = z - (float)zh;
    const _Float16 qh = (_Float16)q2; const float ql = q2 - (float)qh;
    const _Float16 one = (_Float16)1.0f, zero = (_Float16)0.0f;

    H8 a0, a1, b0, b1;
    a0.h[0] = (_Float16)(-2.0f * (float)xh);
    a0.h[1] = (_Float16)(-2.0f * (float)yh);
    a0.h[2] = (_Float16)(-2.0f * (float)zh);
    a0.h[3] = a0.h[0]; a0.h[4] = a0.h[1]; a0.h[5] = a0.h[2];
    a0.h[6] = (_Float16)(-2.0f * xl);
    a0.h[7] = (_Float16)(-2.0f * yl);
    a1.h[0] = (_Float16)(-2.0f * zl);
    a1.h[1] = qh; a1.h[2] = (_Float16)ql;
    a1.h[3] = one; a1.h[4] = one;
    a1.h[5] = zero; a1.h[6] = zero; a1.h[7] = zero;

    b0.h[0] = xh; b0.h[1] = yh; b0.h[2] = zh;
    b0.h[3] = (_Float16)xl; b0.h[4] = (_Float16)yl; b0.h[5] = (_Float16)zl;
    b0.h[6] = xh; b0.h[7] = yh;
    b1.h[0] = zh; b1.h[1] = one; b1.h[2] = one;
    b1.h[3] = qh; b1.h[4] = (_Float16)ql;
    b1.h[5] = zero; b1.h[6] = zero; b1.h[7] = zero;

    Ap[(size_t)i * 2 + 0] = a0.u; Ap[(size_t)i * 2 + 1] = a1.u;
    Bp[(size_t)i * 2 + 0] = b0.u; Bp[(size_t)i * 2 + 1] = b1.u;
}

__global__ __launch_bounds__(BLOCK, 4) void chamfer_mfma(
    const uint4* __restrict__ Ap, const uint4* __restrict__ Bp,
    unsigned* __restrict__ dmin_all)
{
    __shared__ uint4 sB[2][CHUNKB];   // [half][pt]: contiguous 16B/lane reads

    const int tid  = threadIdx.x;
    const int lane = tid & 63;
    const int wid  = tid >> 6;
    const int half = lane >> 5;
    const int lj   = lane & 31;

    const int dir = blockIdx.z;
    const uint4* Arole = Ap + (size_t)dir * NPTS * 2;
    const uint4* Brole = Bp + (size_t)(1 - dir) * NPTS * 2;
    unsigned* dmin = dmin_all + dir * NPTS;

    const int arow0 = blockIdx.x * APB + wid * ROWSW;

    // Two A fragments per wave (rows arow0+lj and arow0+32+lj), resident in 8 VGPRs.
    const half8 af0 = *reinterpret_cast<const half8*>(
        &Arole[((size_t)(arow0 + lj)) * 2 + half]);
    const half8 af1 = *reinterpret_cast<const half8*>(
        &Arole[((size_t)(arow0 + 32 + lj)) * 2 + half]);

    float rmin0[16], rmin1[16];
#pragma unroll
    for (int r = 0; r < 16; ++r) { rmin0[r] = 3.0e38f; rmin1[r] = 3.0e38f; }

    const int bbase = blockIdx.y * BSWEEP;

    for (int s = 0; s < NSTAGE; ++s) {
        __syncthreads();
        // Stage CHUNKB B-points: global [pt][half] -> LDS [half][pt].
        const uint4* src = &Brole[(size_t)(bbase + s * CHUNKB) * 2];
#pragma unroll
        for (int v = tid; v < 2 * CHUNKB; v += BLOCK) {
            sB[v & 1][v >> 1] = src[v];
        }
        __syncthreads();

        const uint4* myB = &sB[half][0];
#pragma unroll 2
        for (int t = 0; t < TPS; t += 2) {
            // One B-pair feeds both A-frags; only one d-tuple pair live at a time.
            const half8 bf0 = *reinterpret_cast<const half8*>(&myB[t * TILE + lj]);
            const half8 bf1 = *reinterpret_cast<const half8*>(&myB[(t + 1) * TILE + lj]);
            floatx16 d0 = __builtin_amdgcn_mfma_f32_32x32x16_f16(af0, bf0, (floatx16)(0.0f), 0, 0, 0);
            floatx16 d1 = __builtin_amdgcn_mfma_f32_32x32x16_f16(af0, bf1, (floatx16)(0.0f), 0, 0, 0);
#pragma unroll
            for (int r = 0; r < 16; ++r)
                rmin0[r] = fminf(fminf(d0[r], d1[r]), rmin0[r]);   // v_min3_f32
            d0 = __builtin_amdgcn_mfma_f32_32x32x16_f16(af1, bf0, (floatx16)(0.0f), 0, 0, 0);
            d1 = __builtin_amdgcn_mfma_f32_32x32x16_f16(af1, bf1, (floatx16)(0.0f), 0, 0, 0);
#pragma unroll
            for (int r = 0; r < 16; ++r)
                rmin1[r] = fminf(fminf(d0[r], d1[r]), rmin1[r]);
        }
    }

    // Butterfly min over the 32 lanes sharing each row set, then merge.
#pragma unroll
    for (int r = 0; r < 16; ++r) {
        float v0 = rmin0[r];
        v0 = fminf(v0, __shfl_xor(v0, 1, 32));
        v0 = fminf(v0, __shfl_xor(v0, 2, 32));
        v0 = fminf(v0, __shfl_xor(v0, 4, 32));
        v0 = fminf(v0, __shfl_xor(v0, 8, 32));
        v0 = fminf(v0, __shfl_xor(v0, 16, 32));
        rmin0[r] = v0;
        float v1 = rmin1[r];
        v1 = fminf(v1, __shfl_xor(v1, 1, 32));
        v1 = fminf(v1, __shfl_xor(v1, 2, 32));
        v1 = fminf(v1, __shfl_xor(v1, 4, 32));
        v1 = fminf(v1, __shfl_xor(v1, 8, 32));
        v1 = fminf(v1, __shfl_xor(v1, 16, 32));
        rmin1[r] = v1;
    }
    if (lj == 0) {
#pragma unroll
        for (int r = 0; r < 16; ++r) {
            const int row = (r & 3) + 8 * (r >> 2) + 4 * half;
            atomicMin(&dmin[arow0 + row],
                      __float_as_uint(fmaxf(rmin0[r], 0.0f)));
            atomicMin(&dmin[arow0 + 32 + row],
                      __float_as_uint(fmaxf(rmin1[r], 0.0f)));
        }
    }
}

__global__ __launch_bounds__(1024) void chamfer_reduce_kernel(
    const unsigned* __restrict__ dmin_all, float* __restrict__ out)
{
    __shared__ double sdata[1024];
    double s = 0.0;
    for (int i = threadIdx.x; i < 2 * NPTS; i += 1024)
        s += (double)__uint_as_float(dmin_all[i]);
    sdata[threadIdx.x] = s;
    __syncthreads();
    for (int off = 512; off > 0; off >>= 1) {
        if (threadIdx.x < off) sdata[threadIdx.x] += sdata[threadIdx.x + off];
        __syncthreads();
    }
    if (threadIdx.x == 0) out[0] = (float)(sdata[0] / (double)NPTS);
}

extern "C" void kernel_launch(void* const* d_in, const int* in_sizes, int n_in,
                              void* d_out, int out_size, void* d_ws, size_t ws_size,
                              hipStream_t stream)
{
    const float* P0 = (const float*)d_in[0];
    const float* P1 = (const float*)d_in[1];
    float* out = (float*)d_out;

    unsigned* dmin = (unsigned*)d_ws;                                     // 128 KB
    uint4* Ap = (uint4*)((char*)d_ws + 2 * NPTS * sizeof(unsigned));      // 1 MB
    uint4* Bp = Ap + (size_t)2 * NPTS * 2;                                // 1 MB

    prep_kernel<<<(2 * NPTS) / 256, 256, 0, stream>>>(P0, P1, Ap, Bp, dmin);

    dim3 grid(NPTS / APB, NBSPLIT, 2);   // 64 x 8 x 2 = 1024 blocks, 4 blocks/CU
    chamfer_mfma<<<grid, BLOCK, 0, stream>>>(Ap, Bp, dmin);

    chamfer_reduce_kernel<<<1, 1024, 0, stream>>>(dmin, out);
}